// Round 8
// baseline (283.197 us; speedup 1.0000x reference)
//
#include <hip/hip_runtime.h>

// Conv2d 5x5 pad=2 stride=1, NCHW fp32 -> fp32, single-term fp16 MFMA.
// X (32,32,128,128), K (64,32,5,5) -> out (32,64,128,128).
//
// R8 vs R7 (126us, MfmaUtil 16.9% = latency-bound):
//  R7's register double-buffer of B was defeated by WAR hazards ->
//  every shift paid full L1/L2 latency (~400cy) for its 4 B-loads.
//  Fix: B staged into LDS in 3-shift chunks via async global_load_lds
//  (16B), double-buffered, ONE __syncthreads per chunk (9 total).
//  Prefetch distance = 3 shifts of compute (~900cy) > L2/L3 latency;
//  the vmcnt(0) drain at the barrier lands AFTER that compute.
//   - B-frag read = lane-consecutive 16B from sK (bank-clean, wave-shared)
//   - tile 16x16 x 64oc, 4 waves x (4 rows x 64 oc): 8 ds_read_b128 +
//     16 MFMA per wave per shift; MFMA wall ~930cy/CU/shift > LDS ~375cy
//  LDS 25600(sX) + 2*12288(sK) = 50176 B -> 3 blocks/CU (12 waves).

#define C_IN 32
#define H 128
#define W 128
#define O_CH 64
#define KS 5
#define PAD 2
#define XH 20
#define XW 20
#define NSHIFT 25
#define CHUNK 3                               // shifts staged per chunk
#define NCHUNKS 9                             // 8*3 + 1 = 25
#define KSLICE_U4 256                         // uint4 per shift-slice (4 KB)
#define KP_ALLOC (27 * KSLICE_U4 * 16)        // padded: chunk 8 stages s=24..26
#define SX_CELLS (XH * 4 * XW)                // 1600 cells of 8ch = 25600 B

typedef _Float16 f16x8 __attribute__((ext_vector_type(8)));
typedef float f32x4 __attribute__((ext_vector_type(4)));

union H8 { _Float16 h[8]; uint4 q; };

// ---- pre-pack K: fp32 OIHW -> Kp uint4[s*256 + nf*64 + (lg*16+lp)],
//      payload = 8ch f16 (c = lg*8+j) of oc = nf*16+lp at shift s ----
__global__ __launch_bounds__(256)
void pack_k_kernel(const float* __restrict__ K, uint4* __restrict__ Kp) {
    int t = blockIdx.x * 256 + threadIdx.x;   // 0..6399
    int lp = t & 15;
    int g  = (t >> 4) & 3;
    int nf = (t >> 6) & 3;
    int s  = t >> 8;                          // 0..24
    int oc = nf * 16 + lp;
    H8 u;
#pragma unroll
    for (int j = 0; j < 8; ++j)
        u.h[j] = (_Float16)K[(size_t)(oc * C_IN + g * 8 + j) * (KS * KS) + s];
    Kp[t] = u.q;
}

// one shifted GEMM step: B from sK chunk buffer, A from sX
static __device__ __forceinline__ void do_shift(const unsigned short* sX,
                                                const unsigned short* sKbuf,
                                                int sc, int s, int wv, int lg,
                                                int lp, int lane,
                                                f32x4 acc[4][4]) {
    const int ky = s / KS, kx = s % KS;
    f16x8 bh[4];
#pragma unroll
    for (int nf = 0; nf < 4; ++nf)
        bh[nf] = *(const f16x8*)&sKbuf[(sc * 256 + nf * 64 + lane) * 8];
    f16x8 ah[4];
#pragma unroll
    for (int mf = 0; mf < 4; ++mf) {
        int off = (((wv * 4 + mf + ky) * 4 + lg) * XW + kx + lp) * 8;
        ah[mf] = *(const f16x8*)&sX[off];
    }
#pragma unroll
    for (int mf = 0; mf < 4; ++mf)
#pragma unroll
        for (int nf = 0; nf < 4; ++nf)
            acc[mf][nf] = __builtin_amdgcn_mfma_f32_16x16x32_f16(
                ah[mf], bh[nf], acc[mf][nf], 0, 0, 0);
}

template<bool USE_KP>
__global__ __launch_bounds__(256, 3)
void conv5x5_f16c(const float* __restrict__ X, const float* __restrict__ K,
                  const uint4* __restrict__ kp4, float* __restrict__ out) {
    __shared__ __align__(16) unsigned short sX[SX_CELLS * 8];      // 25600 B
    __shared__ __align__(16) unsigned short sK[2][CHUNK * 2048];   // 2x12288 B

    const int tid  = threadIdx.x;
    const int lane = tid & 63;
    const int wv   = tid >> 6;      // 0..3: rows wv*4..+3
    const int lg   = lane >> 4;     // 0..3: k-group (channels lg*8..+7)
    const int lp   = lane & 15;

    // XCD-bijective swizzle: each XCD gets a contiguous 256-block run
    // (= 4 whole images) -> halo re-fetch is L2-local.
    const int bid = (blockIdx.x & 7) * 256 + (blockIdx.x >> 3);
    const int n    = bid >> 6;
    const int tile = bid & 63;
    const int ty0  = (tile >> 3) * 16;
    const int tx0  = (tile & 7) * 16;

    // ---- issue async stage of K chunk 0 (s=0..2) into sK[0] ----
    if (USE_KP) {
#pragma unroll
        for (int j = 0; j < CHUNK; ++j)
            __builtin_amdgcn_global_load_lds(
                (const unsigned int*)(kp4 + tid + j * 256),
                (unsigned int*)&((uint4*)sK[0])[tid + j * 256], 16, 0, 0);
    }

    // ---- stage X halo: 32ch x 20y x 20x f16, zero-padded ----
    const float* Xn = X + (size_t)n * C_IN * H * W;
    for (int i = tid; i < SX_CELLS; i += 256) {
        int x = i % XW;
        int t = i / XW;          // = y*4 + g
        int g = t & 3;
        int y = t >> 2;
        int gx = tx0 + x - PAD;
        int gy = ty0 + y - PAD;
        bool inb = ((unsigned)gx < (unsigned)W) && ((unsigned)gy < (unsigned)H);
        const float* p = Xn + (size_t)(g * 8) * (H * W) + gy * W + gx;
        H8 u;
#pragma unroll
        for (int j = 0; j < 8; ++j)
            u.h[j] = (_Float16)(inb ? p[j * (H * W)] : 0.f);
        ((uint4*)sX)[i] = u.q;
    }

    // fallback: build K chunk 0 in LDS from fp32 K (scattered; rare path)
    if (!USE_KP) {
#pragma unroll
        for (int j = 0; j < CHUNK; ++j) {
            int idx = tid + j * 256;          // uint4 slot in buffer
            int s   = idx >> 8;
            int nf  = (idx >> 6) & 3;
            int l   = idx & 63;
            H8 u;
#pragma unroll
            for (int jj = 0; jj < 8; ++jj)
                u.h[jj] = (_Float16)K[(size_t)((nf * 16 + (l & 15)) * C_IN +
                                               (l >> 4) * 8 + jj) * (KS * KS) + s];
            ((uint4*)sK[0])[idx] = u.q;
        }
    }

    f32x4 acc[4][4];
#pragma unroll
    for (int mf = 0; mf < 4; ++mf)
#pragma unroll
        for (int nf = 0; nf < 4; ++nf)
            acc[mf][nf] = (f32x4){0.f, 0.f, 0.f, 0.f};

    __syncthreads();   // sX staged + K chunk 0 landed (barrier drains vmcnt)

    // ---- 9 chunks of 3 shifts (last: 1); prefetch c+1 while computing c ----
#pragma unroll 1
    for (int c = 0; c < NCHUNKS; ++c) {
        const int cur = c & 1;

        if (c < NCHUNKS - 1) {        // stage chunk c+1 into other buffer
            if (USE_KP) {
                const uint4* src = kp4 + (size_t)(c + 1) * (CHUNK * 256);
#pragma unroll
                for (int j = 0; j < CHUNK; ++j)
                    __builtin_amdgcn_global_load_lds(
                        (const unsigned int*)(src + tid + j * 256),
                        (unsigned int*)&((uint4*)sK[cur ^ 1])[tid + j * 256], 16, 0, 0);
            } else {
#pragma unroll
                for (int j = 0; j < CHUNK; ++j) {
                    int idx = tid + j * 256;
                    int s   = (c + 1) * CHUNK + (idx >> 8);
                    if (s < NSHIFT) {
                        int nf = (idx >> 6) & 3;
                        int l  = idx & 63;
                        H8 u;
#pragma unroll
                        for (int jj = 0; jj < 8; ++jj)
                            u.h[jj] = (_Float16)K[(size_t)((nf * 16 + (l & 15)) * C_IN +
                                                           (l >> 4) * 8 + jj) * (KS * KS) + s];
                        ((uint4*)sK[cur ^ 1])[idx] = u.q;
                    }
                }
            }
        }

        // compute the (up to) 3 shifts of this chunk
#pragma unroll
        for (int sc = 0; sc < CHUNK; ++sc) {
            int s = c * CHUNK + sc;
            if (s < NSHIFT)
                do_shift(sX, sK[cur], sc, s, wv, lg, lp, lane, acc);
        }

        __syncthreads();   // drains prefetch vmcnt + protects buffer swap
    }

    // ---- epilogue: C/D col=lane&15=oc-within-16, row=(lane>>4)*4+r = x ----
#pragma unroll
    for (int mf = 0; mf < 4; ++mf) {
        int y = ty0 + wv * 4 + mf;
#pragma unroll
        for (int nf = 0; nf < 4; ++nf) {
            int oc = nf * 16 + lp;
            size_t idx = (((size_t)n * O_CH + oc) * H + y) * W + tx0 + lg * 4;
            *(float4*)&out[idx] = *(float4*)&acc[mf][nf];
        }
    }
}

extern "C" void kernel_launch(void* const* d_in, const int* in_sizes, int n_in,
                              void* d_out, int out_size, void* d_ws, size_t ws_size,
                              hipStream_t stream) {
    const float* X = (const float*)d_in[0];
    const float* K = (const float*)d_in[1];
    float* out = (float*)d_out;

    if (ws_size >= (size_t)KP_ALLOC) {
        uint4* Kp = (uint4*)d_ws;
        pack_k_kernel<<<dim3(25), dim3(256), 0, stream>>>(K, Kp);
        conv5x5_f16c<true><<<dim3(2048), dim3(256), 0, stream>>>(X, K, Kp, out);
    } else {
        conv5x5_f16c<false><<<dim3(2048), dim3(256), 0, stream>>>(X, K, nullptr, out);
    }
}